// Round 1
// baseline (85.612 us; speedup 1.0000x reference)
//
#include <hip/hip_runtime.h>

// T=4 tables, E=500000 rows, D=128 dim, B=4096 bags, L=50 pooling.
// One 64-lane wave per (t, b) bag. Each lane owns output columns {2*lane, 2*lane+1}.
// Per row: wave loads 512B coalesced (uint2/lane), dequant q*scale, accumulate.
// Indices/scales/biases preloaded into lanes 0..49, broadcast via __shfl in the loop
// so row-address computation is register-only and loads pipeline freely.

constexpr int kT = 4;
constexpr int kE = 500000;
constexpr int kD = 128;
constexpr int kB = 4096;
constexpr int kL = 50;

__global__ __launch_bounds__(256, 8)
void embbag_int8_pool_kernel(const unsigned int* __restrict__ idxw,   // indices as 32-bit words
                             const unsigned int* __restrict__ qw,     // [T,E,D] int32 (0..255)
                             const float* __restrict__ scales,        // [T,E]
                             const float* __restrict__ biases,        // [T,E]
                             float* __restrict__ out)                 // [B, T*D] (fp16 ref -> float buf)
{
    const int lane = threadIdx.x & 63;
    const int wave = threadIdx.x >> 6;
    const int w    = blockIdx.x * 4 + wave;      // bag id in [0, T*B)
    const int t    = w >> 12;                    // w / kB   (kB = 4096)
    const int b    = w & (kB - 1);               // w % kB

    // --- detect int64 vs int32 index storage (values in [0, 500000) => int64 high
    // words are all zero; for int32 the odd words are random indices, so the
    // probability all 64 probes are zero is ~(2e-6)^64 ~ 0). Deterministic.
    const unsigned int probe = idxw[2 * lane + 1];
    const int shift = (__ballot(probe != 0) == 0ull) ? 1 : 0;

    // --- preload this bag's L indices + per-row scale/bias into lanes 0..49
    const long long ibase = (long long)(t * kB + b) * kL;
    int   my_idx = 0;
    float my_s   = 0.0f;
    float my_bb  = 0.0f;
    if (lane < kL) {
        my_idx = (int)idxw[(size_t)(ibase + lane) << shift];
        my_s   = scales[(size_t)t * kE + my_idx];
        my_bb  = biases[(size_t)t * kE + my_idx];
    }

    const unsigned int* __restrict__ tbl = qw + (size_t)t * kE * kD;

    float acc0 = 0.0f, acc1 = 0.0f, bsum = 0.0f;
    #pragma unroll 5
    for (int l = 0; l < kL; ++l) {
        const int   idx = __shfl(my_idx, l);
        const float s   = __shfl(my_s,  l);
        const float bb  = __shfl(my_bb, l);
        const uint2 q = *reinterpret_cast<const uint2*>(tbl + (size_t)idx * kD + 2 * lane);
        acc0 = fmaf((float)q.x, s, acc0);
        acc1 = fmaf((float)q.y, s, acc1);
        bsum += bb;
    }

    float2 o;
    o.x = acc0 + bsum;
    o.y = acc1 + bsum;
    *reinterpret_cast<float2*>(out + (size_t)b * (kT * kD) + (size_t)t * kD + 2 * lane) = o;
}

extern "C" void kernel_launch(void* const* d_in, const int* in_sizes, int n_in,
                              void* d_out, int out_size, void* d_ws, size_t ws_size,
                              hipStream_t stream) {
    const unsigned int* idxw   = (const unsigned int*)d_in[0];  // indices [T,B,L] int64-or-int32
    const unsigned int* qw     = (const unsigned int*)d_in[1];  // qweights [T,E,D] int32
    const float*        scales = (const float*)d_in[2];         // [T,E]
    const float*        biases = (const float*)d_in[3];         // [T,E]
    float*              out    = (float*)d_out;                 // [B, T*D]

    const int total_waves = kT * kB;           // 16384 bags, one wave each
    dim3 block(256);                           // 4 waves / block
    dim3 grid(total_waves / 4);                // 4096 blocks
    hipLaunchKernelGGL(embbag_int8_pool_kernel, grid, block, 0, stream,
                       idxw, qw, scales, biases, out);
}

// Round 2
// 84.752 us; speedup vs baseline: 1.0101x; 1.0101x over previous
//
#include <hip/hip_runtime.h>

// T=4 tables, E=500000 rows, D=128 dim, B=4096 bags, L=50 pooling.
// One 64-lane wave per (t,b) bag, lane-split: lanes 0-31 process even rows,
// lanes 32-63 odd rows. Each lane loads uint4 (16B) -> one load instruction
// fetches TWO 512B rows (1KB/wave), 25 load instrs per bag instead of 50.
// Indices/scales/biases preloaded into lanes 0..49 and broadcast via __shfl
// so row addressing is register-only. Halves combined once via __shfl_xor(32).

constexpr int kT = 4;
constexpr int kE = 500000;
constexpr int kD = 128;
constexpr int kB = 4096;
constexpr int kL = 50;

__global__ __launch_bounds__(256, 4)
void embbag_int8_pool_kernel(const unsigned int* __restrict__ idxw,   // indices as 32-bit words
                             const uint4* __restrict__ qw,            // [T,E,D] int32 viewed as uint4
                             const float* __restrict__ scales,        // [T,E]
                             const float* __restrict__ biases,        // [T,E]
                             float* __restrict__ out)                 // [B, T*D]
{
    const int lane = threadIdx.x & 63;
    const int wave = threadIdx.x >> 6;
    const int w    = blockIdx.x * 4 + wave;      // bag id in [0, T*B)
    const int t    = w >> 12;                    // w / kB
    const int b    = w & (kB - 1);               // w % kB

    // int64-vs-int32 index storage detection (values < 500000 => int64 high
    // words all zero; for int32 odd words are random indices => ballot != 0).
    const unsigned int probe = idxw[2 * lane + 1];
    const int shift = (__ballot(probe != 0) == 0ull) ? 1 : 0;

    // preload this bag's L indices + per-row scale/bias into lanes 0..49
    const long long ibase = (long long)(t * kB + b) * kL;
    int   my_idx = 0;
    float my_s   = 0.0f;
    float my_bb  = 0.0f;
    if (lane < kL) {
        my_idx = (int)idxw[(size_t)(ibase + lane) << shift];
        my_s   = scales[(size_t)t * kE + my_idx];
        my_bb  = biases[(size_t)t * kE + my_idx];
    }

    const uint4* __restrict__ tbl = qw + (size_t)t * kE * (kD / 4);
    const int half = lane >> 5;        // 0: even rows, 1: odd rows
    const int sub  = lane & 31;        // column group: cols 4*sub .. 4*sub+3

    float a0 = 0.f, a1 = 0.f, a2 = 0.f, a3 = 0.f, bsum = 0.f;
    #pragma unroll 5
    for (int l = 0; l < kL; l += 2) {
        const int   idx = __shfl(my_idx, l + half);
        const float s   = __shfl(my_s,  l + half);
        const float bb  = __shfl(my_bb, l + half);
        const uint4 q = tbl[(size_t)idx * (kD / 4) + sub];
        a0 = fmaf((float)q.x, s, a0);
        a1 = fmaf((float)q.y, s, a1);
        a2 = fmaf((float)q.z, s, a2);
        a3 = fmaf((float)q.w, s, a3);
        bsum += bb;
    }

    // combine even-row and odd-row halves (both halves end with the full sum)
    a0   += __shfl_xor(a0, 32);
    a1   += __shfl_xor(a1, 32);
    a2   += __shfl_xor(a2, 32);
    a3   += __shfl_xor(a3, 32);
    bsum += __shfl_xor(bsum, 32);

    if (half == 0) {
        float4 o;
        o.x = a0 + bsum;
        o.y = a1 + bsum;
        o.z = a2 + bsum;
        o.w = a3 + bsum;
        *reinterpret_cast<float4*>(out + (size_t)b * (kT * kD) + (size_t)t * kD + 4 * sub) = o;
    }
}

extern "C" void kernel_launch(void* const* d_in, const int* in_sizes, int n_in,
                              void* d_out, int out_size, void* d_ws, size_t ws_size,
                              hipStream_t stream) {
    const unsigned int* idxw   = (const unsigned int*)d_in[0];  // indices [T,B,L] int64-or-int32
    const uint4*        qw     = (const uint4*)d_in[1];         // qweights [T,E,D] int32
    const float*        scales = (const float*)d_in[2];         // [T,E]
    const float*        biases = (const float*)d_in[3];         // [T,E]
    float*              out    = (float*)d_out;                 // [B, T*D]

    const int total_waves = kT * kB;           // 16384 bags, one wave each
    dim3 block(256);                           // 4 waves / block
    dim3 grid(total_waves / 4);                // 4096 blocks
    hipLaunchKernelGGL(embbag_int8_pool_kernel, grid, block, 0, stream,
                       idxw, qw, scales, biases, out);
}